// Round 2
// baseline (2171.873 us; speedup 1.0000x reference)
//
#include <hip/hip_runtime.h>

// Problem constants
#define NC 320          // channels
#define HWN 4096        // H*W
#define NIMG 32         // B*T
#define CHW 1310720ull  // NC*HWN
#define NSEQ 8192       // B*H*W
#define MROWS 131072    // NIMG*HWN

// Workspace layout (float offsets)
#define OFF_BQV   0ull         // [320][640] = [Wqk | wv^T]
#define OFF_WFT   204800ull    // wf^T  [320][320]
#define OFF_WPOT  307200ull    // wpo^T [320][320]
#define OFF_UVEC  409600ull    // wk^T bq (320)
#define OFF_WVEC  409920ull    // wq^T bk (320)
#define OFF_C0    410240ull    // bq.bk (1)
#define OFF_BQVB  410304ull    // bias for [m|v] gemm (640)
#define OFF_ATTN  411008ull    // attn weights 8192*256
#define OFF_BUF1  2508160ull   // m -> n1 -> a2   (131072*320)
#define WS_FLOATS 44451200ull  // ~178 MB (d_out doubles as scratch for v/f)

// ---------------- small precompute kernels ----------------

__global__ void k_vecs(const float* __restrict__ wq, const float* __restrict__ bq,
                       const float* __restrict__ wk, const float* __restrict__ bk,
                       const float* __restrict__ bv,
                       float* __restrict__ uvec, float* __restrict__ wvec,
                       float* __restrict__ c0, float* __restrict__ biasqv) {
    int c = threadIdx.x;  // 0..319
    float su = 0.f, sw = 0.f;
#pragma unroll 4
    for (int o = 0; o < NC; ++o) {
        su += wk[o * NC + c] * bq[o];
        sw += wq[o * NC + c] * bk[o];
    }
    uvec[c] = su;
    wvec[c] = sw;
    biasqv[c] = 0.f;          // m-half: no bias
    biasqv[NC + c] = bv[c];   // v-half: bv
    if (c == 0) {
        float s = 0.f;
        for (int o = 0; o < NC; ++o) s += bq[o] * bk[o];
        c0[0] = s;
    }
}

// Wqk[c1][c2] = sum_o wq[o][c1]*wk[o][c2]  -> Bqv left half (ld 640)
__global__ __launch_bounds__(256) void k_wqk(const float* __restrict__ wq,
                                             const float* __restrict__ wk,
                                             float* __restrict__ Bqv) {
    int idx = blockIdx.x * 256 + threadIdx.x;  // 0..102399
    int c1 = idx / NC, c2 = idx - c1 * NC;
    float s = 0.f;
#pragma unroll 8
    for (int o = 0; o < NC; ++o) s += wq[o * NC + c1] * wk[o * NC + c2];
    Bqv[(size_t)c1 * 640 + c2] = s;
}

// transposes: wv^T into Bqv right half, wf^T, wpo^T
__global__ void k_wT(const float* __restrict__ wv, const float* __restrict__ wf,
                     const float* __restrict__ wpo, float* __restrict__ Bqv,
                     float* __restrict__ wfT, float* __restrict__ wpoT) {
    int idx = blockIdx.x * 256 + threadIdx.x;  // 0..307199
    int m = idx / 102400;
    int rem = idx - m * 102400;
    int c = rem / NC, o = rem - c * NC;
    if (m == 0)      Bqv[(size_t)c * 640 + NC + o] = wv[o * NC + c];
    else if (m == 1) wfT[(size_t)c * NC + o] = wf[o * NC + c];
    else             wpoT[(size_t)c * NC + o] = wpo[o * NC + c];
}

// ---------------- tiled fp32 GEMM ----------------
// C[M x N] = A[M x 320] * B[320 x N] (+bias/epilogue), tile 128x64, BK=32.
// ASRC=1: A rows come straight from x layout (row r = nimg*4096+hw -> x[nimg][k][hw])
// ASRC=0: A is row-major [M][320]
// EPI=0: split write: cols<320 -> O0 (m), cols>=320 -> O1 (v), bias=biasqv
// EPI=1: O0[r][col] = acc + bias[col]
// EPI=2: out[(nimg*320+o)*4096 + hw] = acc + bias[o] + x[same]
template <int ASRC, int EPI>
__global__ __launch_bounds__(256) void k_gemm(const float* __restrict__ Ap,
                                              const float* __restrict__ Bp, int ldb, int NT,
                                              const float* __restrict__ bias,
                                              float* __restrict__ O0, float* __restrict__ O1,
                                              const float* __restrict__ xres) {
    const int tid = threadIdx.x;
    int bx = blockIdx.x;
    int mt = bx / NT, nt = bx - mt * NT;
    int r0 = mt * 128, nb0 = nt * 64;
    int nimg = r0 >> 12;
    int hw0 = r0 & 4095;

    __shared__ float As[32][132];  // [k][m], pad keeps float4 16B-aligned
    __shared__ float Bs[32][64];   // [k][n]

    float acc[8][4];
#pragma unroll
    for (int i = 0; i < 8; ++i)
#pragma unroll
        for (int j = 0; j < 4; ++j) acc[i][j] = 0.f;

    const int tx = tid & 15, ty = tid >> 4;

    for (int k0 = 0; k0 < NC; k0 += 32) {
        if (ASRC == 1) {
            const float* ax = Ap + (size_t)nimg * CHW + hw0;
            int m = tid & 127, kb = tid >> 7;  // kb in {0,1}
#pragma unroll
            for (int j = 0; j < 16; ++j) {
                int k = kb + 2 * j;
                As[k][m] = ax[(size_t)(k0 + k) * HWN + m];
            }
        } else {
            int kk = tid & 31, mb = tid >> 5;  // mb in {0..7}
#pragma unroll
            for (int j = 0; j < 16; ++j) {
                int m = mb + 8 * j;
                As[kk][m] = Ap[(size_t)(r0 + m) * NC + k0 + kk];
            }
        }
        {
            int n = tid & 63, kb = tid >> 6;  // kb in {0..3}
#pragma unroll
            for (int j = 0; j < 8; ++j) {
                int k = kb + 4 * j;
                Bs[k][n] = Bp[(size_t)(k0 + k) * ldb + nb0 + n];
            }
        }
        __syncthreads();
#pragma unroll
        for (int k = 0; k < 32; ++k) {
            float a[8], b[4];
            *(float4*)(&a[0]) = *(const float4*)(&As[k][ty * 8]);
            *(float4*)(&a[4]) = *(const float4*)(&As[k][ty * 8 + 4]);
            *(float4*)(&b[0]) = *(const float4*)(&Bs[k][tx * 4]);
#pragma unroll
            for (int i = 0; i < 8; ++i)
#pragma unroll
                for (int j = 0; j < 4; ++j) acc[i][j] = fmaf(a[i], b[j], acc[i][j]);
        }
        __syncthreads();
    }

    if (EPI <= 1) {
        int col = nb0 + tx * 4;
        float4 bb = *(const float4*)&bias[col];
        float* dst;
        int cc;
        if (EPI == 0) {
            if (nb0 < NC) { dst = O0; cc = col; }
            else          { dst = O1; cc = col - NC; }
        } else { dst = O0; cc = col; }
#pragma unroll
        for (int i = 0; i < 8; ++i) {
            size_t r = (size_t)r0 + ty * 8 + i;
            float4 v4;
            v4.x = acc[i][0] + bb.x;
            v4.y = acc[i][1] + bb.y;
            v4.z = acc[i][2] + bb.z;
            v4.w = acc[i][3] + bb.w;
            *(float4*)&dst[r * NC + cc] = v4;
        }
    } else {
#pragma unroll
        for (int j = 0; j < 4; ++j) {
            int o = nb0 + tx * 4 + j;
            float bb = bias[o];
            size_t obase = ((size_t)nimg * NC + o) * HWN + hw0 + ty * 8;
#pragma unroll
            for (int h = 0; h < 2; ++h) {
                float4 xr = *(const float4*)&xres[obase + h * 4];
                float4 v4;
                v4.x = acc[h * 4 + 0][j] + bb + xr.x;
                v4.y = acc[h * 4 + 1][j] + bb + xr.y;
                v4.z = acc[h * 4 + 2][j] + bb + xr.z;
                v4.w = acc[h * 4 + 3][j] + bb + xr.w;
                *(float4*)&O0[obase + h * 4] = v4;
            }
        }
    }
}

// ---------------- per-sequence scores + softmax ----------------
// scores[t][s] = (m_t . g_s + wg[t] + ug[s] + c0) * 1/sqrt(320), softmax over s
__global__ __launch_bounds__(256) void k_score(const float* __restrict__ x,
                                               const float* __restrict__ mbuf,
                                               const float* __restrict__ uvec,
                                               const float* __restrict__ wvec,
                                               const float* __restrict__ cc0,
                                               float* __restrict__ attn) {
    int bx = blockIdx.x;
    int seq = (bx & 7) * 1024 + (bx >> 3);  // XCD-contiguous swizzle (8192 blocks)
    int b = seq >> 12, hw = seq & 4095;
    const int tid = threadIdx.x;

    __shared__ float gs[16][324], ms[16][324];
    __shared__ float ug[16], wg[16];
    __shared__ float c0s;

    const float* xb = x + (size_t)b * 16 * CHW + hw;
#pragma unroll
    for (int j = 0; j < 20; ++j) {
        int idx = tid + 256 * j;
        int t = idx / 320, c = idx - t * 320;
        gs[t][c] = xb[(size_t)t * CHW + (size_t)c * HWN];
    }
    const float* mb = mbuf + (size_t)b * 16 * CHW + (size_t)hw * NC;
#pragma unroll
    for (int j = 0; j < 5; ++j) {
        int idx = tid + 256 * j;
        int t = idx / 80, c4 = idx - t * 80;
        *(float4*)&ms[t][c4 * 4] = *(const float4*)&mb[(size_t)t * CHW + c4 * 4];
    }
    if (tid == 0) c0s = cc0[0];
    __syncthreads();

    const int t = tid >> 4, grp = tid & 15;
    // bias cross-terms (all lanes participate)
    {
        float pu = 0.f, pw = 0.f;
#pragma unroll
        for (int j = 0; j < 5; ++j) {
            int c = grp * 4 + 64 * j;
            float4 g4 = *(const float4*)&gs[t][c];
            float4 u4 = *(const float4*)&uvec[c];
            float4 w4 = *(const float4*)&wvec[c];
            pu += u4.x * g4.x + u4.y * g4.y + u4.z * g4.z + u4.w * g4.w;
            pw += w4.x * g4.x + w4.y * g4.y + w4.z * g4.z + w4.w * g4.w;
        }
#pragma unroll
        for (int d = 1; d < 16; d <<= 1) {
            pu += __shfl_xor(pu, d, 16);
            pw += __shfl_xor(pw, d, 16);
        }
        if (grp == 0) { ug[t] = pu; wg[t] = pw; }
    }
    __syncthreads();

    const int s = grp;  // tid = t*16 + s
    float acc = 0.f;
#pragma unroll 8
    for (int c4 = 0; c4 < 80; ++c4) {
        float4 m4 = *(const float4*)&ms[t][c4 * 4];
        float4 g4 = *(const float4*)&gs[s][c4 * 4];
        acc += m4.x * g4.x + m4.y * g4.y + m4.z * g4.z + m4.w * g4.w;
    }
    float sc = (acc + wg[t] + ug[s] + c0s) * 0.05590169943749474f;  // 1/sqrt(320)

    float mx = sc;
#pragma unroll
    for (int d = 1; d < 16; d <<= 1) mx = fmaxf(mx, __shfl_xor(mx, d, 16));
    float e = __expf(sc - mx);
    float sm = e;
#pragma unroll
    for (int d = 1; d < 16; d <<= 1) sm += __shfl_xor(sm, d, 16);
    attn[(size_t)seq * 256 + tid] = e / sm;
}

// ---------------- per-sequence attend + residual + LN1 ----------------
__global__ __launch_bounds__(256) void k_att2(const float* __restrict__ x,
                                              const float* __restrict__ attn,
                                              const float* __restrict__ vbuf,
                                              const float* __restrict__ ln1s,
                                              const float* __restrict__ ln1b,
                                              float* __restrict__ n1) {
    int bx = blockIdx.x;
    int seq = (bx & 7) * 1024 + (bx >> 3);
    int b = seq >> 12, hw = seq & 4095;
    const int tid = threadIdx.x;

    __shared__ float gs[16][324], vs[16][324];
    __shared__ float at[256];

    const float* xb = x + (size_t)b * 16 * CHW + hw;
#pragma unroll
    for (int j = 0; j < 20; ++j) {
        int idx = tid + 256 * j;
        int t = idx / 320, c = idx - t * 320;
        gs[t][c] = xb[(size_t)t * CHW + (size_t)c * HWN];
    }
    const float* vb = vbuf + (size_t)b * 16 * CHW + (size_t)hw * NC;
#pragma unroll
    for (int j = 0; j < 5; ++j) {
        int idx = tid + 256 * j;
        int t = idx / 80, c4 = idx - t * 80;
        *(float4*)&vs[t][c4 * 4] = *(const float4*)&vb[(size_t)t * CHW + c4 * 4];
    }
    at[tid] = attn[(size_t)seq * 256 + tid];
    __syncthreads();

    const int t = tid >> 4, grp = tid & 15;
    float4 y4[5];
    float sum = 0.f, sq = 0.f;
#pragma unroll
    for (int j = 0; j < 5; ++j) {
        int c = grp * 4 + 64 * j;
        float4 ao = {0.f, 0.f, 0.f, 0.f};
#pragma unroll
        for (int s2 = 0; s2 < 16; ++s2) {
            float w = at[t * 16 + s2];
            float4 vv = *(const float4*)&vs[s2][c];
            ao.x += w * vv.x; ao.y += w * vv.y; ao.z += w * vv.z; ao.w += w * vv.w;
        }
        float4 g4 = *(const float4*)&gs[t][c];
        float4 y;
        y.x = ao.x + g4.x; y.y = ao.y + g4.y; y.z = ao.z + g4.z; y.w = ao.w + g4.w;
        y4[j] = y;
        sum += y.x + y.y + y.z + y.w;
        sq += y.x * y.x + y.y * y.y + y.z * y.z + y.w * y.w;
    }
#pragma unroll
    for (int d = 1; d < 16; d <<= 1) {
        sum += __shfl_xor(sum, d, 16);
        sq += __shfl_xor(sq, d, 16);
    }
    float mean = sum * (1.f / 320.f);
    float var = sq * (1.f / 320.f) - mean * mean;
    float rstd = rsqrtf(var + 1e-5f);

    float* nrow = n1 + (size_t)b * 16 * CHW + (size_t)hw * NC + (size_t)t * CHW;
#pragma unroll
    for (int j = 0; j < 5; ++j) {
        int c = grp * 4 + 64 * j;
        float4 s4 = *(const float4*)&ln1s[c];
        float4 b4 = *(const float4*)&ln1b[c];
        float4 o;
        o.x = (y4[j].x - mean) * rstd * s4.x + b4.x;
        o.y = (y4[j].y - mean) * rstd * s4.y + b4.y;
        o.z = (y4[j].z - mean) * rstd * s4.z + b4.z;
        o.w = (y4[j].w - mean) * rstd * s4.w + b4.w;
        *(float4*)&nrow[c] = o;
    }
}

// ---------------- residual + LN2: a2 = LN2(n1 + f) -> written over n1 buffer ----------------
__global__ __launch_bounds__(256) void k_ln2(float* __restrict__ n1,
                                             const float* __restrict__ f,
                                             const float* __restrict__ ln2s,
                                             const float* __restrict__ ln2b) {
    const int tid = threadIdx.x;
    const int t = tid >> 4, grp = tid & 15;
    size_t r = (size_t)blockIdx.x * 16 + t;
    float4 y4[5];
    float sum = 0.f, sq = 0.f;
#pragma unroll
    for (int j = 0; j < 5; ++j) {
        int c = grp * 4 + 64 * j;
        float4 a = *(const float4*)&n1[r * NC + c];
        float4 b = *(const float4*)&f[r * NC + c];
        float4 y;
        y.x = a.x + b.x; y.y = a.y + b.y; y.z = a.z + b.z; y.w = a.w + b.w;
        y4[j] = y;
        sum += y.x + y.y + y.z + y.w;
        sq += y.x * y.x + y.y * y.y + y.z * y.z + y.w * y.w;
    }
#pragma unroll
    for (int d = 1; d < 16; d <<= 1) {
        sum += __shfl_xor(sum, d, 16);
        sq += __shfl_xor(sq, d, 16);
    }
    float mean = sum * (1.f / 320.f);
    float var = sq * (1.f / 320.f) - mean * mean;
    float rstd = rsqrtf(var + 1e-5f);
#pragma unroll
    for (int j = 0; j < 5; ++j) {
        int c = grp * 4 + 64 * j;
        float4 s4 = *(const float4*)&ln2s[c];
        float4 b4 = *(const float4*)&ln2b[c];
        float4 o;
        o.x = (y4[j].x - mean) * rstd * s4.x + b4.x;
        o.y = (y4[j].y - mean) * rstd * s4.y + b4.y;
        o.z = (y4[j].z - mean) * rstd * s4.z + b4.z;
        o.w = (y4[j].w - mean) * rstd * s4.w + b4.w;
        *(float4*)&n1[r * NC + c] = o;  // a2 over n1 (n1 dead after this kernel)
    }
}

// ---------------- launch ----------------
extern "C" void kernel_launch(void* const* d_in, const int* in_sizes, int n_in,
                              void* d_out, int out_size, void* d_ws, size_t ws_size,
                              hipStream_t stream) {
    const float* x    = (const float*)d_in[0];
    const float* wq   = (const float*)d_in[5];
    const float* bq   = (const float*)d_in[6];
    const float* wk   = (const float*)d_in[7];
    const float* bk   = (const float*)d_in[8];
    const float* wv   = (const float*)d_in[9];
    const float* bv   = (const float*)d_in[10];
    const float* ln1s = (const float*)d_in[11];
    const float* ln1b = (const float*)d_in[12];
    const float* wf   = (const float*)d_in[13];
    const float* bf   = (const float*)d_in[14];
    const float* ln2s = (const float*)d_in[15];
    const float* ln2b = (const float*)d_in[16];
    const float* wpo  = (const float*)d_in[17];
    const float* bpo  = (const float*)d_in[18];

    float* ws = (float*)d_ws;
    float* Bqv    = ws + OFF_BQV;
    float* wfT    = ws + OFF_WFT;
    float* wpoT   = ws + OFF_WPOT;
    float* uvec   = ws + OFF_UVEC;
    float* wvec   = ws + OFF_WVEC;
    float* c0     = ws + OFF_C0;
    float* biasqv = ws + OFF_BQVB;
    float* attn   = ws + OFF_ATTN;
    float* buf1   = ws + OFF_BUF1;  // m -> n1 -> a2
    float* out    = (float*)d_out;  // also scratch for v -> f

    k_vecs<<<1, 320, 0, stream>>>(wq, bq, wk, bk, bv, uvec, wvec, c0, biasqv);
    k_wqk<<<400, 256, 0, stream>>>(wq, wk, Bqv);
    k_wT<<<1200, 256, 0, stream>>>(wv, wf, wpo, Bqv, wfT, wpoT);

    // [m | v] = g @ [Wqk | wv^T] (+ [0|bv]);  m -> buf1, v -> d_out (scratch)
    k_gemm<1, 0><<<1024 * 10, 256, 0, stream>>>(x, Bqv, 640, 10, biasqv, buf1, out, nullptr);

    k_score<<<8192, 256, 0, stream>>>(x, buf1, uvec, wvec, c0, attn);
    // att2 reads v from d_out, writes n1 over buf1 (m dead)
    k_att2<<<8192, 256, 0, stream>>>(x, attn, out, ln1s, ln1b, buf1);

    // f = n1 @ wf^T + bf -> d_out (v dead)
    k_gemm<0, 1><<<1024 * 5, 256, 0, stream>>>(buf1, wfT, 320, 5, bf, out, nullptr, nullptr);
    // a2 = LN2(n1 + f) -> over buf1 (n1 dead)
    k_ln2<<<8192, 256, 0, stream>>>(buf1, out, ln2s, ln2b);
    // out = a2 @ wpo^T + bpo + x (scattered back to (n,c,h,w)) -> d_out
    k_gemm<0, 2><<<1024 * 5, 256, 0, stream>>>(buf1, wpoT, 320, 5, bpo, out, nullptr, x);
}

// Round 8
// 1318.341 us; speedup vs baseline: 1.6474x; 1.6474x over previous
//
#include <hip/hip_runtime.h>
#include <hip/hip_bf16.h>

typedef float f32x4 __attribute__((ext_vector_type(4)));
typedef short bf16x8 __attribute__((ext_vector_type(8)));

#define NC 320
#define HWN 4096
#define CHW 1310720ull  // NC*HWN

// workspace byte offsets
#define OFF_B1H   0ull          // [640][320] bf16 hi = 409600 B
#define OFF_B1L   409600ull
#define OFF_B2H   819200ull     // [320][320] bf16
#define OFF_B2L   1024000ull
#define OFF_B3H   1228800ull
#define OFF_B3L   1433600ull
#define OFF_BIASQV 1638400ull   // 640 f32
#define OFF_UVEC  1640960ull    // 320 f32
#define OFF_WVEC  1642240ull
#define OFF_C0    1643520ull
#define OFF_BUF1  2097152ull              // 131072*320*4 = 167772160 B (mT -> n1T -> a2T)
#define OFF_GT    169869312ull            // gT fp32, 167772160 B
#define NEED_BIG  337641472ull

__device__ inline void cvt_hl(float f, unsigned short& h, unsigned short& l) {
    __hip_bfloat16 hb = __float2bfloat16(f);
    float hf = __bfloat162float(hb);
    __hip_bfloat16 lb = __float2bfloat16(f - hf);
    h = __builtin_bit_cast(unsigned short, hb);
    l = __builtin_bit_cast(unsigned short, lb);
}

// ---------------- precompute: uvec/wvec/c0/biasqv (fp32) ----------------
__global__ void k_vecs(const float* __restrict__ wq, const float* __restrict__ bq,
                       const float* __restrict__ wk, const float* __restrict__ bk,
                       const float* __restrict__ bv,
                       float* __restrict__ uvec, float* __restrict__ wvec,
                       float* __restrict__ c0, float* __restrict__ biasqv) {
    int c = threadIdx.x;  // 0..319
    float su = 0.f, sw = 0.f;
#pragma unroll 4
    for (int o = 0; o < NC; ++o) {
        su += wk[o * NC + c] * bq[o];
        sw += wq[o * NC + c] * bk[o];
    }
    uvec[c] = su;
    wvec[c] = sw;
    biasqv[c] = 0.f;
    biasqv[NC + c] = bv[c];
    if (c == 0) {
        float s = 0.f;
        for (int o = 0; o < NC; ++o) s += bq[o] * bk[o];
        c0[0] = s;
    }
}

// B1T[n][k]: n<320 -> Wqk[k][n] = sum_o wq[o][k]*wk[o][n]; n>=320 -> wv[n-320][k]
__global__ __launch_bounds__(256) void k_prepB1(const float* __restrict__ wq,
                                                const float* __restrict__ wk,
                                                const float* __restrict__ wv,
                                                unsigned short* __restrict__ B1h,
                                                unsigned short* __restrict__ B1l) {
    int idx = blockIdx.x * 256 + threadIdx.x;  // 0..204799
    int n = idx / NC, k = idx - n * NC;
    float s;
    if (n < NC) {
        s = 0.f;
#pragma unroll 8
        for (int o = 0; o < NC; ++o) s += wq[o * NC + k] * wk[o * NC + n];
    } else {
        s = wv[(n - NC) * NC + k];
    }
    cvt_hl(s, B1h[idx], B1l[idx]);
}

// B2T = wf rows, B3T = wpo rows (already [o][k] layout), cvt to hi/lo
__global__ __launch_bounds__(256) void k_prepB23(const float* __restrict__ wf,
                                                 const float* __restrict__ wpo,
                                                 unsigned short* __restrict__ B2h,
                                                 unsigned short* __restrict__ B2l,
                                                 unsigned short* __restrict__ B3h,
                                                 unsigned short* __restrict__ B3l) {
    int idx = blockIdx.x * 256 + threadIdx.x;  // 0..204799
    int sel = idx >= 102400;
    int rem = idx - sel * 102400;
    const float* src = sel ? wpo : wf;
    unsigned short* dh = sel ? B3h : B2h;
    unsigned short* dl = sel ? B3l : B2l;
    cvt_hl(src[rem], dh[rem], dl[rem]);
}

// ---------------- x -> gT[b][hw][t][c] fp32 transpose ----------------
__global__ __launch_bounds__(256) void k_gt(const float* __restrict__ x,
                                            float* __restrict__ gT) {
    // grid 5120 = 16(hw-chunk) * 10(c-chunk) * 16(t) * 2(b)
    int bx = blockIdx.x;
    int hwc = bx & 15;          int hw0 = hwc * 256;
    int rest = bx >> 4;
    int cc = rest % 10;         int c0 = cc * 32;
    int rest2 = rest / 10;
    int t = rest2 & 15, b = rest2 >> 4;
    const int tid = threadIdx.x;

    __shared__ float ts[32][257];
    const float* src = x + (size_t)(b * 16 + t) * CHW + hw0;
#pragma unroll
    for (int j = 0; j < 32; ++j) ts[j][tid] = src[(size_t)(c0 + j) * HWN + tid];
    __syncthreads();
    int cl = tid & 31;
#pragma unroll
    for (int p = 0; p < 32; ++p) {
        int hwl = (tid >> 5) + p * 8;
        gT[(size_t)(b * 4096 + hw0 + hwl) * 5120 + t * NC + c0 + cl] = ts[cl][hwl];
    }
}

// ---------------- split-bf16 MFMA GEMM ----------------
// C[M x N] = A[M x 320] * B[320 x N] via hi/lo bf16 decomposition (3 MFMAs/frag).
// Tile 128x64, BK=64, 256 threads (4 waves, 2x2 wave grid, each 64x32).
// ASRC=1: A[r][k] = x[img][k][hw]  (r = img*4096+hw)
// ASRC=2: A[r][k] = Ap[(b*4096+hw)*5120 + t*320 + k]  (pixel-major layout)
// EPI=0: cols<320 -> O0 in pixel-major mT layout; cols>=320 -> O1 row-major (v); bias=biasqv
// EPI=1: O0[r][c] = acc + bias[c] (row-major)
// EPI=2: O0[(img*320+o)*4096+hw] = acc + bias[o] + xres[same]  (LDS-transposed store)
template <int ASRC, int EPI>
__global__ __launch_bounds__(256) void k_gemm_mfma(
    const float* __restrict__ Ap, const unsigned short* __restrict__ BTh,
    const unsigned short* __restrict__ BTl, int NT,
    const float* __restrict__ bias, float* __restrict__ O0,
    float* __restrict__ O1, const float* __restrict__ xres) {
    __shared__ __align__(16) char smem[49152];
    unsigned short* As_h = (unsigned short*)smem;   // [128][64]
    unsigned short* As_l = As_h + 8192;
    unsigned short* Bs_h = As_h + 16384;            // [64][64]
    unsigned short* Bs_l = As_h + 20480;

    const int tid = threadIdx.x;
    const int nwg = gridDim.x;
    const int bx = blockIdx.x;
    const int wg = (bx & 7) * (nwg >> 3) + (bx >> 3);  // XCD-chunked swizzle (nwg%8==0)
    const int mt = wg / NT, nt = wg - mt * NT;
    const int r0 = mt * 128, nb0 = nt * 64;
    const int img = r0 >> 12, hw0 = r0 & 4095;
    const int b4096 = (img >> 4) * 4096, tl = img & 15;

    f32x4 acc[4][2];
#pragma unroll
    for (int i = 0; i < 4; ++i)
#pragma unroll
        for (int j = 0; j < 2; ++j) acc[i][j] = (f32x4){0.f, 0.f, 0.f, 0.f};

    const int l = tid & 63, wid = tid >> 6;
    const int wm = wid >> 1, wn = wid & 1;
    const int lrow = l & 15;
    const int lk = (l >> 4) * 8;
    const int swzf = (lrow & 7) << 3;

    const int sm = tid & 127;          // A staging row
    const int skh = (tid >> 7) * 32;   // A staging k-half
    const int sn = tid & 63;           // B staging row (n)
    const int skq = (tid >> 6) * 16;   // B staging k base

    for (int k0 = 0; k0 < NC; k0 += 64) {
        // stage A (fp32 -> hi/lo bf16, swizzled)
#pragma unroll
        for (int g = 0; g < 4; ++g) {
            int kb = k0 + skh + g * 8;
            float v[8];
            if (ASRC == 1) {
                const float* src = Ap + (size_t)img * CHW + hw0 + sm;
#pragma unroll
                for (int i = 0; i < 8; ++i) v[i] = src[(size_t)(kb + i) * HWN];
            } else {
                const float* src = Ap + (size_t)(b4096 + hw0 + sm) * 5120 + tl * NC + kb;
                *(float4*)&v[0] = *(const float4*)src;
                *(float4*)&v[4] = *(const float4*)(src + 4);
            }
            unsigned short hu[8], lu[8];
#pragma unroll
            for (int i = 0; i < 8; ++i) cvt_hl(v[i], hu[i], lu[i]);
            uint4 wh, wl;
            wh.x = (unsigned)hu[0] | ((unsigned)hu[1] << 16);
            wh.y = (unsigned)hu[2] | ((unsigned)hu[3] << 16);
            wh.z = (unsigned)hu[4] | ((unsigned)hu[5] << 16);
            wh.w = (unsigned)hu[6] | ((unsigned)hu[7] << 16);
            wl.x = (unsigned)lu[0] | ((unsigned)lu[1] << 16);
            wl.y = (unsigned)lu[2] | ((unsigned)lu[3] << 16);
            wl.z = (unsigned)lu[4] | ((unsigned)lu[5] << 16);
            wl.w = (unsigned)lu[6] | ((unsigned)lu[7] << 16);
            int bi = (sm * 64 + skh + g * 8) ^ ((sm & 7) << 3);
            *(uint4*)&As_h[bi] = wh;
            *(uint4*)&As_l[bi] = wl;
        }
        // stage B (bf16 hi/lo copy, swizzled)
        {
            const unsigned short* sh = BTh + (size_t)(nb0 + sn) * NC + k0 + skq;
            const unsigned short* sl = BTl + (size_t)(nb0 + sn) * NC + k0 + skq;
            uint4 h0 = *(const uint4*)sh;
            uint4 h1 = *(const uint4*)(sh + 8);
            uint4 l0 = *(const uint4*)sl;
            uint4 l1 = *(const uint4*)(sl + 8);
            int bi0 = (sn * 64 + skq) ^ ((sn & 7) << 3);
            int bi1 = (sn * 64 + skq + 8) ^ ((sn & 7) << 3);
            *(uint4*)&Bs_h[bi0] = h0;
            *(uint4*)&Bs_h[bi1] = h1;
            *(uint4*)&Bs_l[bi0] = l0;
            *(uint4*)&Bs_l[bi1] = l1;
        }
        __syncthreads();
#pragma unroll
        for (int kk = 0; kk < 64; kk += 32) {
            int ko = kk + lk;
            bf16x8 ah[4], al[4], bh[2], bl[2];
#pragma unroll
            for (int mf = 0; mf < 4; ++mf) {
                int idx = ((wm * 64 + mf * 16 + lrow) * 64 + ko) ^ swzf;
                ah[mf] = *(const bf16x8*)&As_h[idx];
                al[mf] = *(const bf16x8*)&As_l[idx];
            }
#pragma unroll
            for (int nf = 0; nf < 2; ++nf) {
                int idx = ((wn * 32 + nf * 16 + lrow) * 64 + ko) ^ swzf;
                bh[nf] = *(const bf16x8*)&Bs_h[idx];
                bl[nf] = *(const bf16x8*)&Bs_l[idx];
            }
#pragma unroll
            for (int mf = 0; mf < 4; ++mf)
#pragma unroll
                for (int nf = 0; nf < 2; ++nf) {
                    acc[mf][nf] = __builtin_amdgcn_mfma_f32_16x16x32_bf16(ah[mf], bh[nf], acc[mf][nf], 0, 0, 0);
                    acc[mf][nf] = __builtin_amdgcn_mfma_f32_16x16x32_bf16(ah[mf], bl[nf], acc[mf][nf], 0, 0, 0);
                    acc[mf][nf] = __builtin_amdgcn_mfma_f32_16x16x32_bf16(al[mf], bh[nf], acc[mf][nf], 0, 0, 0);
                }
        }
        __syncthreads();
    }

    if (EPI == 0) {
#pragma unroll
        for (int mf = 0; mf < 4; ++mf)
#pragma unroll
            for (int nf = 0; nf < 2; ++nf) {
                int c = nb0 + wn * 32 + nf * 16 + lrow;
                float bb = bias[c];
#pragma unroll
                for (int j = 0; j < 4; ++j) {
                    int r = r0 + wm * 64 + mf * 16 + (l >> 4) * 4 + j;
                    float val = acc[mf][nf][j] + bb;
                    if (nb0 < NC)
                        O0[(size_t)(b4096 + (r & 4095)) * 5120 + tl * NC + c] = val;  // mT
                    else
                        O1[(size_t)r * NC + (c - NC)] = val;  // v row-major
                }
            }
    } else if (EPI == 1) {
#pragma unroll
        for (int mf = 0; mf < 4; ++mf)
#pragma unroll
            for (int nf = 0; nf < 2; ++nf) {
                int c = nb0 + wn * 32 + nf * 16 + lrow;
                float bb = bias[c];
#pragma unroll
                for (int j = 0; j < 4; ++j) {
                    int r = r0 + wm * 64 + mf * 16 + (l >> 4) * 4 + j;
                    O0[(size_t)r * NC + c] = acc[mf][nf][j] + bb;
                }
            }
    } else {
        float* Cs = (float*)smem;  // [64][132]
#pragma unroll
        for (int mf = 0; mf < 4; ++mf)
#pragma unroll
            for (int nf = 0; nf < 2; ++nf) {
                int lc = wn * 32 + nf * 16 + lrow;
#pragma unroll
                for (int j = 0; j < 4; ++j) {
                    int lr = wm * 64 + mf * 16 + (l >> 4) * 4 + j;
                    Cs[lc * 132 + lr] = acc[mf][nf][j];
                }
            }
        __syncthreads();
        int m4 = (tid & 31) * 4;
        int ol = tid >> 5;
#pragma unroll
        for (int p = 0; p < 8; ++p) {
            int o = ol + p * 8;
            float4 cv = *(float4*)&Cs[o * 132 + m4];
            float bb = bias[nb0 + o];
            size_t addr = ((size_t)img * NC + nb0 + o) * HWN + hw0 + m4;
            float4 xr = *(const float4*)&xres[addr];
            float4 ov;
            ov.x = cv.x + bb + xr.x;
            ov.y = cv.y + bb + xr.y;
            ov.z = cv.z + bb + xr.z;
            ov.w = cv.w + bb + xr.w;
            *(float4*)&O0[addr] = ov;
        }
    }
}

// ---------------- fused attention: scores+softmax+attend+residual+LN1 ----------------
// GSRC=1: g from gT (coalesced); GSRC=0: g gathered from x (fallback)
template <int GSRC>
__global__ __launch_bounds__(256) void k_attn(const float* __restrict__ x,
                                              const float* __restrict__ gT,
                                              const float* __restrict__ mT,
                                              const float* __restrict__ vbuf,
                                              const float* __restrict__ uvec,
                                              const float* __restrict__ wvec,
                                              const float* __restrict__ cc0,
                                              const float* __restrict__ ln1s,
                                              const float* __restrict__ ln1b,
                                              float* __restrict__ n1T) {
    int bx = blockIdx.x;
    int seq = (bx & 7) * 1024 + (bx >> 3);
    int b = seq >> 12, hw = seq & 4095;
    const int tid = threadIdx.x;

    __shared__ float gs[16][324], ms[16][324], vs[16][324];
    __shared__ float at[256], ug[16], wg[16];
    __shared__ float c0s;

    if (GSRC == 1) {
        const float* g0 = gT + (size_t)seq * 5120;
#pragma unroll
        for (int j = 0; j < 5; ++j) {
            int idx = tid + 256 * j;
            int t = idx / 80, c4 = idx - t * 80;
            *(float4*)&gs[t][c4 * 4] = *(const float4*)&g0[(size_t)idx * 4];
        }
    } else {
        const float* xb = x + (size_t)b * 16 * CHW + hw;
#pragma unroll
        for (int j = 0; j < 20; ++j) {
            int idx = tid + 256 * j;
            int t = idx / 320, c = idx - t * 320;
            gs[t][c] = xb[(size_t)t * CHW + (size_t)c * HWN];
        }
    }
    {
        const float* m0 = mT + (size_t)seq * 5120;
#pragma unroll
        for (int j = 0; j < 5; ++j) {
            int idx = tid + 256 * j;
            int t = idx / 80, c4 = idx - t * 80;
            *(float4*)&ms[t][c4 * 4] = *(const float4*)&m0[(size_t)idx * 4];
        }
#pragma unroll
        for (int j = 0; j < 5; ++j) {
            int idx = tid + 256 * j;
            int t = idx / 80, c4 = idx - t * 80;
            *(float4*)&vs[t][c4 * 4] =
                *(const float4*)&vbuf[((size_t)(b * 16 + t) * HWN + hw) * NC + c4 * 4];
        }
    }
    if (tid == 0) c0s = cc0[0];
    __syncthreads();

    const int t = tid >> 4, grp = tid & 15;
    {
        float pu = 0.f, pw = 0.f;
#pragma unroll
        for (int j = 0; j < 5; ++j) {
            int c = grp * 4 + 64 * j;
            float4 g4 = *(const float4*)&gs[t][c];
            float4 u4 = *(const float4*)&uvec[c];
            float4 w4 = *(const float4*)&wvec[c];
            pu += u4.x * g4.x + u4.y * g4.y + u4.z * g4.z + u4.w * g4.w;
            pw += w4.x * g4.x + w4.y * g4.y + w4.z * g4.z + w4.w * g4.w;
        }
#pragma unroll
        for (int d = 1; d < 16; d <<= 1) {
            pu += __shfl_xor(pu, d, 16);
            pw += __shfl_xor(pw, d, 16);
        }
        if (grp == 0) { ug[t] = pu; wg[t] = pw; }
    }
    __syncthreads();

    const int s = grp;
    float dacc = 0.f;
#pragma unroll 8
    for (int c4 = 0; c4 < 80; ++c4) {
        float4 m4 = *(const float4*)&ms[t][c4 * 4];
        float4 g4 = *(const float4*)&gs[s][c4 * 4];
        dacc += m4.x * g4.x + m4.y * g4.y + m4.z * g4.z + m4.w * g4.w;
    }
    float sc = (dacc + wg[t] + ug[s] + c0s) * 0.05590169943749474f;  // 1/sqrt(320)
    float mx = sc;
#pragma unroll
    for (int d = 1; d < 16; d <<= 1) mx = fmaxf(mx, __shfl_xor(mx, d, 16));
    float e = __expf(sc - mx);
    float smv = e;
#pragma unroll
    for (int d = 1; d < 16; d <<= 1) smv += __shfl_xor(smv, d, 16);
    at[tid] = e / smv;
    __syncthreads();

    float4 y4[5];
    float sum = 0.f, sq = 0.f;
#pragma unroll
    for (int j = 0; j < 5; ++j) {
        int c = grp * 4 + 64 * j;
        float4 ao = {0.f, 0.f, 0.f, 0.f};
#pragma unroll
        for (int s2 = 0; s2 < 16; ++s2) {
            float w = at[t * 16 + s2];
            float4 vv = *(const float4*)&vs[s2][c];
            ao.x += w * vv.x; ao.y += w * vv.y; ao.z += w * vv.z; ao.w += w * vv.w;
        }
        float4 g4 = *(const float4*)&gs[t][c];
        float4 y;
        y.x = ao.x + g4.x; y.y = ao.y + g4.y; y.z = ao.z + g4.z; y.w = ao.w + g4.w;
        y4[j] = y;
        sum += y.x + y.y + y.z + y.w;
        sq += y.x * y.x + y.y * y.y + y.z * y.z + y.w * y.w;
    }
#pragma unroll
    for (int d = 1; d < 16; d <<= 1) {
        sum += __shfl_xor(sum, d, 16);
        sq += __shfl_xor(sq, d, 16);
    }
    float mean = sum * (1.f / 320.f);
    float var = sq * (1.f / 320.f) - mean * mean;
    float rstd = rsqrtf(var + 1e-5f);

    float* nrow = n1T + (size_t)seq * 5120 + t * NC;
#pragma unroll
    for (int j = 0; j < 5; ++j) {
        int c = grp * 4 + 64 * j;
        float4 s4 = *(const float4*)&ln1s[c];
        float4 b4 = *(const float4*)&ln1b[c];
        float4 o;
        o.x = (y4[j].x - mean) * rstd * s4.x + b4.x;
        o.y = (y4[j].y - mean) * rstd * s4.y + b4.y;
        o.z = (y4[j].z - mean) * rstd * s4.z + b4.z;
        o.w = (y4[j].w - mean) * rstd * s4.w + b4.w;
        *(float4*)&nrow[c] = o;
    }
}

// ---------------- a2 = LN2(n1 + f), in-place over n1T (pixel-major) ----------------
__global__ __launch_bounds__(256) void k_ln2p(float* __restrict__ n1T,
                                              const float* __restrict__ f,
                                              const float* __restrict__ ln2s,
                                              const float* __restrict__ ln2b) {
    int bx = blockIdx.x;
    int seq = (bx & 7) * 1024 + (bx >> 3);
    int b = seq >> 12, hw = seq & 4095;
    const int tid = threadIdx.x;
    const int t = tid >> 4, grp = tid & 15;

    float* nrow = n1T + (size_t)seq * 5120 + t * NC;
    const float* frow = f + ((size_t)(b * 16 + t) * HWN + hw) * NC;
    float4 y4[5];
    float sum = 0.f, sq = 0.f;
#pragma unroll
    for (int j = 0; j < 5; ++j) {
        int c = grp * 4 + 64 * j;
        float4 a = *(const float4*)&nrow[c];
        float4 bb = *(const float4*)&frow[c];
        float4 y;
        y.x = a.x + bb.x; y.y = a.y + bb.y; y.z = a.z + bb.z; y.w = a.w + bb.w;
        y4[j] = y;
        sum += y.x + y.y + y.z + y.w;
        sq += y.x * y.x + y.y * y.y + y.z * y.z + y.w * y.w;
    }
#pragma unroll
    for (int d = 1; d < 16; d <<= 1) {
        sum += __shfl_xor(sum, d, 16);
        sq += __shfl_xor(sq, d, 16);
    }
    float mean = sum * (1.f / 320.f);
    float var = sq * (1.f / 320.f) - mean * mean;
    float rstd = rsqrtf(var + 1e-5f);
#pragma unroll
    for (int j = 0; j < 5; ++j) {
        int c = grp * 4 + 64 * j;
        float4 s4 = *(const float4*)&ln2s[c];
        float4 b4 = *(const float4*)&ln2b[c];
        float4 o;
        o.x = (y4[j].x - mean) * rstd * s4.x + b4.x;
        o.y = (y4[j].y - mean) * rstd * s4.y + b4.y;
        o.z = (y4[j].z - mean) * rstd * s4.z + b4.z;
        o.w = (y4[j].w - mean) * rstd * s4.w + b4.w;
        *(float4*)&nrow[c] = o;
    }
}

// ---------------- launch ----------------
extern "C" void kernel_launch(void* const* d_in, const int* in_sizes, int n_in,
                              void* d_out, int out_size, void* d_ws, size_t ws_size,
                              hipStream_t stream) {
    const float* x    = (const float*)d_in[0];
    const float* wq   = (const float*)d_in[5];
    const float* bq   = (const float*)d_in[6];
    const float* wk   = (const float*)d_in[7];
    const float* bk   = (const float*)d_in[8];
    const float* wv   = (const float*)d_in[9];
    const float* bv   = (const float*)d_in[10];
    const float* ln1s = (const float*)d_in[11];
    const float* ln1b = (const float*)d_in[12];
    const float* wf   = (const float*)d_in[13];
    const float* bf   = (const float*)d_in[14];
    const float* ln2s = (const float*)d_in[15];
    const float* ln2b = (const float*)d_in[16];
    const float* wpo  = (const float*)d_in[17];
    const float* bpo  = (const float*)d_in[18];

    char* ws = (char*)d_ws;
    unsigned short* B1h = (unsigned short*)(ws + OFF_B1H);
    unsigned short* B1l = (unsigned short*)(ws + OFF_B1L);
    unsigned short* B2h = (unsigned short*)(ws + OFF_B2H);
    unsigned short* B2l = (unsigned short*)(ws + OFF_B2L);
    unsigned short* B3h = (unsigned short*)(ws + OFF_B3H);
    unsigned short* B3l = (unsigned short*)(ws + OFF_B3L);
    float* biasqv = (float*)(ws + OFF_BIASQV);
    float* uvec   = (float*)(ws + OFF_UVEC);
    float* wvec   = (float*)(ws + OFF_WVEC);
    float* c0     = (float*)(ws + OFF_C0);
    float* buf1   = (float*)(ws + OFF_BUF1);  // mT -> n1T -> a2T (pixel-major)
    float* gTp    = (float*)(ws + OFF_GT);
    float* out    = (float*)d_out;            // scratch: v -> f -> final
    const bool big = ws_size >= NEED_BIG;

    k_vecs<<<1, 320, 0, stream>>>(wq, bq, wk, bk, bv, uvec, wvec, c0, biasqv);
    k_prepB1<<<800, 256, 0, stream>>>(wq, wk, wv, B1h, B1l);
    k_prepB23<<<800, 256, 0, stream>>>(wf, wpo, B2h, B2l, B3h, B3l);
    if (big) k_gt<<<5120, 256, 0, stream>>>(x, gTp);

    // [m | v] = g @ [Wqk | wv^T] + [0|bv];  m -> buf1 (pixel-major), v -> d_out (row-major)
    k_gemm_mfma<1, 0><<<10240, 256, 0, stream>>>(x, B1h, B1l, 10, biasqv, buf1, out, nullptr);

    if (big)
        k_attn<1><<<8192, 256, 0, stream>>>(x, gTp, buf1, out, uvec, wvec, c0, ln1s, ln1b, buf1);
    else
        k_attn<0><<<8192, 256, 0, stream>>>(x, gTp, buf1, out, uvec, wvec, c0, ln1s, ln1b, buf1);

    // f = n1 @ wf^T + bf -> d_out (row-major; v dead)
    k_gemm_mfma<2, 1><<<5120, 256, 0, stream>>>(buf1, B2h, B2l, 5, bf, out, nullptr, nullptr);
    // a2 = LN2(n1 + f) in-place over buf1
    k_ln2p<<<8192, 256, 0, stream>>>(buf1, out, ln2s, ln2b);
    // out = a2 @ wpo^T + bpo + x  (scatter to (n,c,h,w))
    k_gemm_mfma<2, 2><<<5120, 256, 0, stream>>>(buf1, B3h, B3l, 5, bpo, out, nullptr, x);
}